// Round 7
// baseline (556.490 us; speedup 1.0000x reference)
//
#include <hip/hip_runtime.h>
#include <hip/hip_cooperative_groups.h>

namespace cg = cooperative_groups;

// Problem constants (fixed by setup_inputs)
#define NNODES 50000
#define NEDGES 800000
#define DIM    128
#define NRELS  4               // edge relations; weight slice 4 = self-loop
#define NB     (NRELS*NNODES)  // 200000 (rel,dst) bins
#define NBLKS  98              // scan chunks: 98*2048 = 200704 >= NB+1
#define METAB  512             // cooperative meta-kernel blocks (2/CU, co-resident)

typedef __attribute__((ext_vector_type(8))) short bf16x8;
typedef __attribute__((ext_vector_type(8))) unsigned short u16x8;
typedef __attribute__((ext_vector_type(4))) float f32x4;

// ---- ws layout (bytes) ----
#define SSRC_OFF   0            // u32[NEDGES+16]        3,200,064
#define CNT_OFF    3200256      // u32[200704]             802,816 (bins -> excl scan)
#define BSUM_OFF   4003072      // u32[128]
#define CTRL_OFF   4003584      // u32[64]: [8..12] tile offsets per rel
#define LHIST_OFF  4003840      // u32[256] (rel,lenb) histogram
#define LBASE_OFF  4004864      // u32[256] slot base per (rel,lenb) bin
#define GCUR_OFF   4005888      // u32[256] running cursor per bin
#define SSTART_OFF 4006912      // u32[NSLOTS]             800,512
#define SLEN_OFF   4807424      // u32[NSLOTS]             800,512
#define CUR_OFF    5607936      // u32[NB]                 800,256
#define SLOTOF_OFF 6408192      // u32[NB] (0xFFFFFFFF = empty)  800,256
#define WT_OFF     7208448      // bf16[5*128*128]         163,840
#define XBF_OFF    7372288      // bf16[NNODES*DIM]     12,800,000
#define GMAX_OFF   20172288     // bf16[NSLOTS*128]     51,232,768 -> total ~71.4 MB
#define NZERO      ((SLOTOF_OFF - CNT_OFF) / 4)  // 801,984 u32 zeroed

__device__ __forceinline__ unsigned short f2bf(float f) {  // RNE f32->bf16
  unsigned u = __float_as_uint(f);
  return (unsigned short)((u + 0x7FFFu + ((u >> 16) & 1u)) >> 16);
}
__device__ __forceinline__ float bf2f(unsigned short u) {
  return __uint_as_float(((unsigned)u) << 16);
}

// ---- prep: x f32->bf16, W transpose+convert, zero ctrl region, slotof=-1 ----
__global__ void k_prep(const float* __restrict__ x, unsigned short* __restrict__ xbf,
                       const float* __restrict__ W, unsigned short* __restrict__ Wt,
                       unsigned* __restrict__ z, unsigned* __restrict__ sf) {
  int i = blockIdx.x * blockDim.x + threadIdx.x;
  if (i < NNODES * DIM / 8) {
    const float4* p = (const float4*)x + i * 2;
    float4 v0 = p[0], v1 = p[1];
    u16x8 o;
    o[0] = f2bf(v0.x); o[1] = f2bf(v0.y); o[2] = f2bf(v0.z); o[3] = f2bf(v0.w);
    o[4] = f2bf(v1.x); o[5] = f2bf(v1.y); o[6] = f2bf(v1.z); o[7] = f2bf(v1.w);
    *(u16x8*)(xbf + i * 8) = o;
  }
  if (i < 5 * DIM * DIM) {
    int r = i >> 14, rem = i & 16383, k = rem >> 7, c = rem & 127;
    Wt[(r << 14) + (c << 7) + k] = f2bf(W[i]);
  }
  if (i < NZERO) z[i] = 0u;
  if (i < NB) sf[i] = 0xFFFFFFFFu;
}

// ---- cooperative meta kernel: hist -> scan(+lhist) -> lscan -> gfill + scat ----
// Replaces 7 separate launches (each dispatch cost ~20 us of gap in rounds 2-6).
__global__ __launch_bounds__(256, 2) void k_meta(
    const int* __restrict__ rel, const int* __restrict__ dst, const int* __restrict__ src,
    unsigned* __restrict__ cnt, unsigned* __restrict__ bsum, unsigned* __restrict__ ctrl,
    unsigned* __restrict__ lhist, unsigned* __restrict__ lbase, unsigned* __restrict__ gcur,
    unsigned* __restrict__ sstart, unsigned* __restrict__ slen, unsigned* __restrict__ cur,
    unsigned* __restrict__ slotof, unsigned* __restrict__ ssrc) {
  cg::grid_group gg = cg::this_grid();
  int tid = threadIdx.x;
  int gtid = blockIdx.x * 256 + tid;
  int gstride = gridDim.x * 256;
  __shared__ unsigned sh[256];
  __shared__ unsigned sh2[256];
  __shared__ unsigned pbs[NRELS], rex[NRELS];

  // P1: (rel,dst) histogram
  for (int e = gtid; e < NEDGES; e += gstride) {
    int r = rel[e]; r = r < 0 ? 0 : (r > NRELS - 1 ? NRELS - 1 : r);
    atomicAdd(&cnt[r * NNODES + dst[e]], 1u);
  }
  gg.sync();

  // P2: block-local exclusive scan of 2048-chunks + (rel,len) histogram (LDS-aggregated)
  if (blockIdx.x < NBLKS) {
    int base = blockIdx.x * 2048 + tid * 8;
    unsigned v[8], tsum = 0;
#pragma unroll
    for (int j = 0; j < 8; j++) { v[j] = cnt[base + j]; tsum += v[j]; }
    sh2[tid] = 0u;
    __syncthreads();
#pragma unroll
    for (int j = 0; j < 8; j++) {
      int b = base + j;
      if (v[j] && b < NB) {
        int r = b / NNODES;
        atomicAdd(&sh2[(r << 6) + (int)min(v[j], 63u)], 1u);
      }
    }
    sh[tid] = tsum;
    __syncthreads();
    for (int off = 1; off < 256; off <<= 1) {
      unsigned t = (tid >= off) ? sh[tid - off] : 0u;
      __syncthreads();
      sh[tid] += t;
      __syncthreads();
    }
    unsigned run = sh[tid] - tsum;
#pragma unroll
    for (int j = 0; j < 8; j++) { unsigned t = v[j]; cnt[base + j] = run; run += t; }
    if (tid == 255) bsum[blockIdx.x] = sh[255];
    if (sh2[tid]) atomicAdd(&lhist[tid], sh2[tid]);
  }
  gg.sync();

  // P3 (block 0): exclusive scan of bsum; scan of lhist -> lbase + per-rel tile offsets
  if (blockIdx.x == 0) {
    unsigned bv = (tid < NBLKS) ? bsum[tid] : 0u;
    sh[tid] = (tid < 128) ? bv : 0u;
    __syncthreads();
    for (int off = 1; off < 128; off <<= 1) {
      unsigned t = (tid >= off && tid < 128) ? sh[tid - off] : 0u;
      __syncthreads();
      if (tid < 128) sh[tid] += t;
      __syncthreads();
    }
    if (tid < NBLKS) bsum[tid] = sh[tid] - bv;  // exclusive block prefix
    __syncthreads();
    unsigned v = lhist[tid];
    sh[tid] = v;
    __syncthreads();
    for (int off = 1; off < 256; off <<= 1) {
      unsigned t = (tid >= off) ? sh[tid - off] : 0u;
      __syncthreads();
      sh[tid] += t;
      __syncthreads();
    }
    unsigned ex = sh[tid] - v;
    if (tid == 0) {
      unsigned tt = 0;
      ctrl[8] = 0;
      for (int r = 0; r < NRELS; r++) {
        unsigned hi = sh[r * 64 + 63];
        unsigned lo = (r == 0) ? 0u : sh[r * 64 - 1];
        rex[r] = lo;
        pbs[r] = tt * 16u;            // slot base of rel region (16-aligned)
        tt += (hi - lo + 15u) / 16u;  // tiles for this rel
        ctrl[9 + r] = tt;
      }
    }
    __syncthreads();
    lbase[tid] = pbs[tid >> 6] + (ex - rex[tid >> 6]);
  }
  gg.sync();

  // P4: add block prefix to chunks
  if (blockIdx.x > 0 && blockIdx.x < NBLKS) {
    unsigned p = bsum[blockIdx.x];
    int base = blockIdx.x * 2048 + tid * 8;
#pragma unroll
    for (int j = 0; j < 8; j++) cnt[base + j] += p;
  }
  gg.sync();

  // P5a: gfill (LDS-ranked; 1 global atomic per block,bin)
  for (int b0 = blockIdx.x * 256; b0 < NB; b0 += gstride) {
    sh[tid] = 0u;
    __syncthreads();
    int b = b0 + tid;
    unsigned start = 0, len = 0, loc = 0;
    int bin = 0;
    if (b < NB) {
      start = cnt[b];
      len = cnt[b + 1] - start;
      if (len) {
        int r = b / NNODES;
        bin = (r << 6) + (int)min(len, 63u);
        loc = atomicAdd(&sh[bin], 1u);
      }
    }
    __syncthreads();
    unsigned hv = sh[tid];
    sh2[tid] = hv ? atomicAdd(&gcur[tid], hv) : 0u;
    __syncthreads();
    if (len) {
      unsigned slot = lbase[bin] + sh2[bin] + loc;
      sstart[slot] = start;
      slen[slot] = len;
      slotof[b] = slot;  // b = r*NNODES + dst: the lookup key k_node needs
    }
    __syncthreads();
  }
  // P5b: scatter src values into (rel,dst)-sorted edge order (indep of gfill)
  for (int e = gtid; e < NEDGES; e += gstride) {
    int r = rel[e]; r = r < 0 ? 0 : (r > NRELS - 1 ? NRELS - 1 : r);
    int key = r * NNODES + dst[e];
    unsigned pos = cnt[key] + atomicAdd(&cur[key], 1u);
    ssrc[pos] = (unsigned)src[e];
  }
}

// ---- group GEMM + per-group max -> plain bf16 stores to gmax ----
// Length-sorted slots => uniform steps per tile; one-step x-row prefetch (double-buffered
// A registers) so the gather for step+1 is in flight during step's MFMA block.
__global__ __launch_bounds__(256, 2) void k_edge(
    const unsigned short* __restrict__ xbf, const unsigned short* __restrict__ Wt,
    const float* __restrict__ bias, const unsigned* __restrict__ ssrc,
    const unsigned* __restrict__ sstart, const unsigned* __restrict__ slen,
    const unsigned* __restrict__ ctrl, unsigned short* __restrict__ gmax) {
  int lane = threadIdx.x & 63;
  int wid = blockIdx.x * (blockDim.x >> 6) + (threadIdx.x >> 6);
  int nw = gridDim.x * (blockDim.x >> 6);
  int gt1 = (int)ctrl[9], gt2 = (int)ctrl[10], gt3 = (int)ctrl[11];
  int T = (int)ctrl[12];
  int col = lane & 15, quad = lane >> 4;
  bf16x8 B[8][4];
  float bs[8];
  int rcur = -1;

  for (int t = wid; t < T; t += nw) {
    int r = (t >= gt1) + (t >= gt2) + (t >= gt3);
    if (r != rcur) {
      rcur = r;
      const unsigned short* wr = Wt + (r << 14);
#pragma unroll
      for (int ct = 0; ct < 8; ct++) {
#pragma unroll
        for (int kk = 0; kk < 4; kk++)
          B[ct][kk] = *(const bf16x8*)(wr + ((ct * 16 + col) << 7) + kk * 32 + quad * 8);
        bs[ct] = bias[(r << 7) + ct * 16 + col];
      }
    }
    int sbase = t * 16;
    unsigned astart = sstart[sbase + col];   // this lane's A-row group
    int alen = (int)slen[sbase + col];
    int aclamp = alen > 0 ? alen - 1 : 0;
    f32x4 mx[8];
#pragma unroll
    for (int ct = 0; ct < 8; ct++) mx[ct] = (f32x4){-3.0e38f, -3.0e38f, -3.0e38f, -3.0e38f};

    // preload row 0
    unsigned sa = ssrc[astart];  // padding rows: slen=0, sstart=0 -> valid dummy
    const unsigned short* xr = xbf + ((size_t)sa << 7);
    bf16x8 c0 = *(const bf16x8*)(xr + quad * 8);
    bf16x8 c1 = *(const bf16x8*)(xr + 32 + quad * 8);
    bf16x8 c2 = *(const bf16x8*)(xr + 64 + quad * 8);
    bf16x8 c3 = *(const bf16x8*)(xr + 96 + quad * 8);
    int step = 0;
    while (__any(step < alen)) {
      bf16x8 a0 = c0, a1 = c1, a2 = c2, a3 = c3;
      unsigned sa2 = ssrc[astart + min(step + 1, aclamp)];
      const unsigned short* xr2 = xbf + ((size_t)sa2 << 7);
      c0 = *(const bf16x8*)(xr2 + quad * 8);
      c1 = *(const bf16x8*)(xr2 + 32 + quad * 8);
      c2 = *(const bf16x8*)(xr2 + 64 + quad * 8);
      c3 = *(const bf16x8*)(xr2 + 96 + quad * 8);
#pragma unroll
      for (int ct = 0; ct < 8; ct++) {
        f32x4 acc = {0.f, 0.f, 0.f, 0.f};
        acc = __builtin_amdgcn_mfma_f32_16x16x32_bf16(a0, B[ct][0], acc, 0, 0, 0);
        acc = __builtin_amdgcn_mfma_f32_16x16x32_bf16(a1, B[ct][1], acc, 0, 0, 0);
        acc = __builtin_amdgcn_mfma_f32_16x16x32_bf16(a2, B[ct][2], acc, 0, 0, 0);
        acc = __builtin_amdgcn_mfma_f32_16x16x32_bf16(a3, B[ct][3], acc, 0, 0, 0);
#pragma unroll
        for (int j = 0; j < 4; j++) mx[ct][j] = fmaxf(mx[ct][j], acc[j]);
      }
      step++;
    }
#pragma unroll
    for (int ct = 0; ct < 8; ct++) {
#pragma unroll
      for (int j = 0; j < 4; j++) {
        size_t idx = ((size_t)(sbase + quad * 4 + j) << 7) + (unsigned)(ct * 16 + col);
        gmax[idx] = f2bf(mx[ct][j] + bs[ct]);
      }
    }
  }
}

// ---- self-loop GEMM + fused cross-rel max reduce (<=4 slots/node) + store f32 ----
__global__ __launch_bounds__(256, 2) void k_node(
    const unsigned short* __restrict__ x, const unsigned short* __restrict__ Wt,
    const float* __restrict__ bias, const unsigned* __restrict__ slotof,
    const unsigned short* __restrict__ gmax, float* __restrict__ out) {
  int lane = threadIdx.x & 63;
  int wid = blockIdx.x * (blockDim.x >> 6) + (threadIdx.x >> 6);
  int col = lane & 15, quad = lane >> 4;
  int row0 = wid * 16;
  if (row0 >= NNODES) return;

  const unsigned short* wr = Wt + (4 << 14);
  bf16x8 B[8][4];
  float bs[8];
#pragma unroll
  for (int ct = 0; ct < 8; ct++) {
#pragma unroll
    for (int kk = 0; kk < 4; kk++)
      B[ct][kk] = *(const bf16x8*)(wr + ((ct * 16 + col) << 7) + kk * 32 + quad * 8);
    bs[ct] = bias[(4 << 7) + ct * 16 + col];
  }
  int na = min(row0 + col, NNODES - 1);
  bf16x8 a0 = *(const bf16x8*)(x + (na << 7) + quad * 8);
  bf16x8 a1 = *(const bf16x8*)(x + (na << 7) + 32 + quad * 8);
  bf16x8 a2 = *(const bf16x8*)(x + (na << 7) + 64 + quad * 8);
  bf16x8 a3 = *(const bf16x8*)(x + (na << 7) + 96 + quad * 8);

  unsigned sl[4][NRELS];
  bool anyv[4];
#pragma unroll
  for (int j = 0; j < 4; j++) {
    int n = row0 + quad * 4 + j;
    bool a = false;
#pragma unroll
    for (int r = 0; r < NRELS; r++) {
      unsigned s = slotof[r * NNODES + n];
      sl[j][r] = s;
      a |= (s != 0xFFFFFFFFu);
    }
    anyv[j] = a;
  }

#pragma unroll
  for (int ct = 0; ct < 8; ct++) {
    f32x4 acc = {0.f, 0.f, 0.f, 0.f};
    acc = __builtin_amdgcn_mfma_f32_16x16x32_bf16(a0, B[ct][0], acc, 0, 0, 0);
    acc = __builtin_amdgcn_mfma_f32_16x16x32_bf16(a1, B[ct][1], acc, 0, 0, 0);
    acc = __builtin_amdgcn_mfma_f32_16x16x32_bf16(a2, B[ct][2], acc, 0, 0, 0);
    acc = __builtin_amdgcn_mfma_f32_16x16x32_bf16(a3, B[ct][3], acc, 0, 0, 0);
#pragma unroll
    for (int j = 0; j < 4; j++) {
      int n = row0 + quad * 4 + j;
      float m = -3.0e38f;
#pragma unroll
      for (int r = 0; r < NRELS; r++) {
        unsigned s = sl[j][r];
        if (s != 0xFFFFFFFFu)
          m = fmaxf(m, bf2f(gmax[((size_t)s << 7) + (unsigned)(ct * 16 + col)]));
      }
      float av = anyv[j] ? m : 0.f;  // DGL zero-fill for nodes w/o in-edges
      out[((size_t)n << 7) + (unsigned)(ct * 16 + col)] = acc[j] + bs[ct] + av;
    }
  }
}

extern "C" void kernel_launch(void* const* d_in, const int* in_sizes, int n_in,
                              void* d_out, int out_size, void* d_ws, size_t ws_size,
                              hipStream_t stream) {
  const float* x = (const float*)d_in[0];
  const float* W = (const float*)d_in[1];
  const float* bias = (const float*)d_in[2];
  const int* src = (const int*)d_in[3];
  const int* dst = (const int*)d_in[4];
  const int* rel = (const int*)d_in[5];

  char* ws = (char*)d_ws;
  unsigned* ssrc = (unsigned*)(ws + SSRC_OFF);
  unsigned* cnt = (unsigned*)(ws + CNT_OFF);
  unsigned* bsum = (unsigned*)(ws + BSUM_OFF);
  unsigned* ctrl = (unsigned*)(ws + CTRL_OFF);
  unsigned* lhist = (unsigned*)(ws + LHIST_OFF);
  unsigned* lbase = (unsigned*)(ws + LBASE_OFF);
  unsigned* gcur = (unsigned*)(ws + GCUR_OFF);
  unsigned* sstart = (unsigned*)(ws + SSTART_OFF);
  unsigned* slen = (unsigned*)(ws + SLEN_OFF);
  unsigned* cur = (unsigned*)(ws + CUR_OFF);
  unsigned* slotof = (unsigned*)(ws + SLOTOF_OFF);
  unsigned short* Wt = (unsigned short*)(ws + WT_OFF);
  unsigned short* xbf = (unsigned short*)(ws + XBF_OFF);
  unsigned short* gmax = (unsigned short*)(ws + GMAX_OFF);

  hipLaunchKernelGGL(k_prep, dim3(3133), dim3(256), 0, stream, x, xbf, W, Wt, cnt, slotof);

  void* margs[] = {(void*)&rel,    (void*)&dst,  (void*)&src,   (void*)&cnt,  (void*)&bsum,
                   (void*)&ctrl,   (void*)&lhist, (void*)&lbase, (void*)&gcur, (void*)&sstart,
                   (void*)&slen,   (void*)&cur,  (void*)&slotof, (void*)&ssrc};
  hipLaunchCooperativeKernel((const void*)k_meta, dim3(METAB), dim3(256), margs, 0, stream);

  hipLaunchKernelGGL(k_edge, dim3(2048), dim3(256), 0, stream, xbf, Wt, bias, ssrc, sstart, slen,
                     ctrl, gmax);
  hipLaunchKernelGGL(k_node, dim3(782), dim3(256), 0, stream, xbf, Wt, bias, slotof, gmax,
                     (float*)d_out);
}

// Round 8
// 328.493 us; speedup vs baseline: 1.6941x; 1.6941x over previous
//
#include <hip/hip_runtime.h>

// Problem constants (fixed by setup_inputs)
#define NNODES 50000
#define NEDGES 800000
#define DIM    128
#define NRELS  4               // edge relations; weight slice 4 = self-loop
#define NB     (NRELS*NNODES)  // 200000 (rel,dst) bins
#define NBLKS  98              // scan chunks: 98*2048 = 200704 >= NB+1

typedef __attribute__((ext_vector_type(8))) short bf16x8;
typedef __attribute__((ext_vector_type(8))) unsigned short u16x8;
typedef __attribute__((ext_vector_type(4))) float f32x4;

// ---- ws layout (bytes) ----
#define SSRC_OFF   0            // u32[NEDGES+16]        3,200,064
#define CNT_OFF    3200256      // u32[200704]             802,816 (bins -> excl scan)
#define BSUM_OFF   4003072      // u32[128]
#define CTRL_OFF   4003584      // u32[64]: [8..12] tile offsets per rel
#define LHIST_OFF  4003840      // u32[256] (rel,lenb) histogram
#define LBASE_OFF  4004864      // u32[256] slot base per (rel,lenb) bin
#define GCUR_OFF   4005888      // u32[256] running cursor per bin
#define SSTART_OFF 4006912      // u32[NSLOTS]             800,512
#define SLEN_OFF   4807424      // u32[NSLOTS]             800,512
#define CUR_OFF    5607936      // u32[NB]                 800,256
#define SLOTOF_OFF 6408192      // u32[NB] (0xFFFFFFFF = empty)  800,256
#define WT_OFF     7208448      // bf16[5*128*128]         163,840
#define XBF_OFF    7372288      // bf16[NNODES*DIM]     12,800,000
#define GMAX_OFF   20172288     // bf16[NSLOTS*128]     51,232,768 -> total ~71.4 MB
#define NZ2        ((SLOTOF_OFF - BSUM_OFF) / 4)  // 601,280 u32 zeroed in k_prep

__device__ __forceinline__ unsigned short f2bf(float f) {  // RNE f32->bf16
  unsigned u = __float_as_uint(f);
  return (unsigned short)((u + 0x7FFFu + ((u >> 16) & 1u)) >> 16);
}
__device__ __forceinline__ float bf2f(unsigned short u) {
  return __uint_as_float(((unsigned)u) << 16);
}

// ---- prep: x f32->bf16, W transpose+convert, zero scan metadata, slotof=-1,
//      AND (rel,dst) histogram (cnt was zeroed by the preceding hipMemsetAsync) ----
__global__ void k_prep(const float* __restrict__ x, unsigned short* __restrict__ xbf,
                       const float* __restrict__ W, unsigned short* __restrict__ Wt,
                       const int* __restrict__ rel, const int* __restrict__ dst,
                       unsigned* __restrict__ cnt, unsigned* __restrict__ z2,
                       unsigned* __restrict__ sf) {
  int i = blockIdx.x * blockDim.x + threadIdx.x;
  if (i < NNODES * DIM / 8) {
    const float4* p = (const float4*)x + i * 2;
    float4 v0 = p[0], v1 = p[1];
    u16x8 o;
    o[0] = f2bf(v0.x); o[1] = f2bf(v0.y); o[2] = f2bf(v0.z); o[3] = f2bf(v0.w);
    o[4] = f2bf(v1.x); o[5] = f2bf(v1.y); o[6] = f2bf(v1.z); o[7] = f2bf(v1.w);
    *(u16x8*)(xbf + i * 8) = o;
  }
  if (i < 5 * DIM * DIM) {
    int r = i >> 14, rem = i & 16383, k = rem >> 7, c = rem & 127;
    Wt[(r << 14) + (c << 7) + k] = f2bf(W[i]);
  }
  if (i < NZ2) z2[i] = 0u;
  if (i < NB) sf[i] = 0xFFFFFFFFu;
  if (i < NEDGES) {
    int r = rel[i]; r = r < 0 ? 0 : (r > NRELS - 1 ? NRELS - 1 : r);
    atomicAdd(&cnt[r * NNODES + dst[i]], 1u);
  }
}

// ---- block-local exclusive scan of 2048-chunks, in place + fused (rel,len) histogram ----
__global__ void k_scanA(unsigned* __restrict__ cnt, unsigned* __restrict__ bsum,
                        unsigned* __restrict__ lhist) {
  __shared__ unsigned sh[256];
  __shared__ unsigned sh2[256];
  int tid = threadIdx.x;
  int base = blockIdx.x * 2048 + tid * 8;
  unsigned v[8], tsum = 0;
#pragma unroll
  for (int j = 0; j < 8; j++) { v[j] = cnt[base + j]; tsum += v[j]; }
  sh2[tid] = 0u;
  __syncthreads();
#pragma unroll
  for (int j = 0; j < 8; j++) {
    int b = base + j;
    if (v[j] && b < NB) {
      int r = b / NNODES;
      atomicAdd(&sh2[(r << 6) + (int)min(v[j], 63u)], 1u);
    }
  }
  sh[tid] = tsum;
  __syncthreads();
  for (int off = 1; off < 256; off <<= 1) {
    unsigned t = (tid >= off) ? sh[tid - off] : 0u;
    __syncthreads();
    sh[tid] += t;
    __syncthreads();
  }
  unsigned run = sh[tid] - tsum;
#pragma unroll
  for (int j = 0; j < 8; j++) { unsigned t = v[j]; cnt[base + j] = run; run += t; }
  if (tid == 255) bsum[blockIdx.x] = sh[255];
  if (sh2[tid]) atomicAdd(&lhist[tid], sh2[tid]);
}

// ---- fused: blocks 0..NBLKS-1 add block-prefix to chunks; block NBLKS does lscan ----
__global__ void k_fix(unsigned* __restrict__ cnt, const unsigned* __restrict__ bsum,
                      const unsigned* __restrict__ lhist, unsigned* __restrict__ lbase,
                      unsigned* __restrict__ ctrl) {
  int blk = blockIdx.x;
  int tid = threadIdx.x;
  if (blk < NBLKS) {
    if (blk == 0) return;
    unsigned p = 0;
    for (int k = 0; k < blk; k++) p += bsum[k];
    int base = blk * 2048 + tid * 8;
#pragma unroll
    for (int j = 0; j < 8; j++) cnt[base + j] += p;
    return;
  }
  // lscan: scan of 256 (rel,lenb) bins -> per-bin slot base + per-rel tile offsets.
  // Slots within a rel ordered by length bucket => tiles have near-uniform group len.
  __shared__ unsigned sh[256];
  __shared__ unsigned pbs[NRELS], rex[NRELS];
  unsigned v = lhist[tid];
  sh[tid] = v;
  __syncthreads();
  for (int off = 1; off < 256; off <<= 1) {
    unsigned t = (tid >= off) ? sh[tid - off] : 0u;
    __syncthreads();
    sh[tid] += t;
    __syncthreads();
  }
  unsigned ex = sh[tid] - v;  // exclusive prefix
  if (tid == 0) {
    unsigned tt = 0;
    ctrl[8] = 0;
    for (int r = 0; r < NRELS; r++) {
      unsigned hi = sh[r * 64 + 63];
      unsigned lo = (r == 0) ? 0u : sh[r * 64 - 1];
      rex[r] = lo;
      pbs[r] = tt * 16u;            // slot base of rel region (16-aligned)
      tt += (hi - lo + 15u) / 16u;  // tiles for this rel
      ctrl[9 + r] = tt;
    }
  }
  __syncthreads();
  lbase[tid] = pbs[tid >> 6] + (ex - rex[tid >> 6]);
}

// ---- fused: blocks 0..781 gfill (LDS-ranked slots); blocks 782.. scat src values ----
__global__ void k_fill(const int* __restrict__ rel, const int* __restrict__ dst,
                       const int* __restrict__ src, const unsigned* __restrict__ cnt,
                       const unsigned* __restrict__ lbase, unsigned* __restrict__ gcur,
                       unsigned* __restrict__ sstart, unsigned* __restrict__ slen,
                       unsigned* __restrict__ slotof, unsigned* __restrict__ cur,
                       unsigned* __restrict__ ssrc) {
  int tid = threadIdx.x;
  if (blockIdx.x < 782) {
    __shared__ unsigned h[256], basearr[256];
    h[tid] = 0u;
    __syncthreads();
    int b = blockIdx.x * 256 + tid;
    unsigned start = 0, len = 0, loc = 0;
    int bin = 0;
    if (b < NB) {
      start = cnt[b];
      len = cnt[b + 1] - start;
      if (len) {
        int r = b / NNODES;
        bin = (r << 6) + (int)min(len, 63u);
        loc = atomicAdd(&h[bin], 1u);
      }
    }
    __syncthreads();
    unsigned hv = h[tid];
    basearr[tid] = hv ? atomicAdd(&gcur[tid], hv) : 0u;
    __syncthreads();
    if (len) {
      unsigned slot = lbase[bin] + basearr[bin] + loc;
      sstart[slot] = start;
      slen[slot] = len;
      slotof[b] = slot;  // b = r*NNODES + dst: the lookup key k_node needs
    }
  } else {
    int e = (blockIdx.x - 782) * 256 + tid;
    if (e < NEDGES) {
      int r = rel[e]; r = r < 0 ? 0 : (r > NRELS - 1 ? NRELS - 1 : r);
      int key = r * NNODES + dst[e];
      unsigned pos = cnt[key] + atomicAdd(&cur[key], 1u);
      ssrc[pos] = (unsigned)src[e];
    }
  }
}

// ---- group GEMM + per-group max -> plain bf16 stores to gmax ----
// Length-sorted slots => uniform steps per tile; one-step x-row prefetch (double-buffered
// A registers) so the gather for step+1 is in flight during step's MFMA block.
__global__ __launch_bounds__(256, 2) void k_edge(
    const unsigned short* __restrict__ xbf, const unsigned short* __restrict__ Wt,
    const float* __restrict__ bias, const unsigned* __restrict__ ssrc,
    const unsigned* __restrict__ sstart, const unsigned* __restrict__ slen,
    const unsigned* __restrict__ ctrl, unsigned short* __restrict__ gmax) {
  int lane = threadIdx.x & 63;
  int wid = blockIdx.x * (blockDim.x >> 6) + (threadIdx.x >> 6);
  int nw = gridDim.x * (blockDim.x >> 6);
  int gt1 = (int)ctrl[9], gt2 = (int)ctrl[10], gt3 = (int)ctrl[11];
  int T = (int)ctrl[12];
  int col = lane & 15, quad = lane >> 4;
  bf16x8 B[8][4];
  float bs[8];
  int rcur = -1;

  for (int t = wid; t < T; t += nw) {
    int r = (t >= gt1) + (t >= gt2) + (t >= gt3);
    if (r != rcur) {
      rcur = r;
      const unsigned short* wr = Wt + (r << 14);
#pragma unroll
      for (int ct = 0; ct < 8; ct++) {
#pragma unroll
        for (int kk = 0; kk < 4; kk++)
          B[ct][kk] = *(const bf16x8*)(wr + ((ct * 16 + col) << 7) + kk * 32 + quad * 8);
        bs[ct] = bias[(r << 7) + ct * 16 + col];
      }
    }
    int sbase = t * 16;
    unsigned astart = sstart[sbase + col];   // this lane's A-row group
    int alen = (int)slen[sbase + col];
    int aclamp = alen > 0 ? alen - 1 : 0;
    f32x4 mx[8];
#pragma unroll
    for (int ct = 0; ct < 8; ct++) mx[ct] = (f32x4){-3.0e38f, -3.0e38f, -3.0e38f, -3.0e38f};

    // preload row 0
    unsigned sa = ssrc[astart];  // padding rows: slen=0, sstart=0 -> valid dummy
    const unsigned short* xr = xbf + ((size_t)sa << 7);
    bf16x8 c0 = *(const bf16x8*)(xr + quad * 8);
    bf16x8 c1 = *(const bf16x8*)(xr + 32 + quad * 8);
    bf16x8 c2 = *(const bf16x8*)(xr + 64 + quad * 8);
    bf16x8 c3 = *(const bf16x8*)(xr + 96 + quad * 8);
    int step = 0;
    while (__any(step < alen)) {
      bf16x8 a0 = c0, a1 = c1, a2 = c2, a3 = c3;
      unsigned sa2 = ssrc[astart + min(step + 1, aclamp)];
      const unsigned short* xr2 = xbf + ((size_t)sa2 << 7);
      c0 = *(const bf16x8*)(xr2 + quad * 8);
      c1 = *(const bf16x8*)(xr2 + 32 + quad * 8);
      c2 = *(const bf16x8*)(xr2 + 64 + quad * 8);
      c3 = *(const bf16x8*)(xr2 + 96 + quad * 8);
#pragma unroll
      for (int ct = 0; ct < 8; ct++) {
        f32x4 acc = {0.f, 0.f, 0.f, 0.f};
        acc = __builtin_amdgcn_mfma_f32_16x16x32_bf16(a0, B[ct][0], acc, 0, 0, 0);
        acc = __builtin_amdgcn_mfma_f32_16x16x32_bf16(a1, B[ct][1], acc, 0, 0, 0);
        acc = __builtin_amdgcn_mfma_f32_16x16x32_bf16(a2, B[ct][2], acc, 0, 0, 0);
        acc = __builtin_amdgcn_mfma_f32_16x16x32_bf16(a3, B[ct][3], acc, 0, 0, 0);
#pragma unroll
        for (int j = 0; j < 4; j++) mx[ct][j] = fmaxf(mx[ct][j], acc[j]);
      }
      step++;
    }
#pragma unroll
    for (int ct = 0; ct < 8; ct++) {
#pragma unroll
      for (int j = 0; j < 4; j++) {
        size_t idx = ((size_t)(sbase + quad * 4 + j) << 7) + (unsigned)(ct * 16 + col);
        gmax[idx] = f2bf(mx[ct][j] + bs[ct]);
      }
    }
  }
}

// ---- self-loop GEMM + fused cross-rel max reduce (<=4 slots/node) + store f32 ----
__global__ __launch_bounds__(256, 2) void k_node(
    const unsigned short* __restrict__ x, const unsigned short* __restrict__ Wt,
    const float* __restrict__ bias, const unsigned* __restrict__ slotof,
    const unsigned short* __restrict__ gmax, float* __restrict__ out) {
  int lane = threadIdx.x & 63;
  int wid = blockIdx.x * (blockDim.x >> 6) + (threadIdx.x >> 6);
  int col = lane & 15, quad = lane >> 4;
  int row0 = wid * 16;
  if (row0 >= NNODES) return;

  const unsigned short* wr = Wt + (4 << 14);
  bf16x8 B[8][4];
  float bs[8];
#pragma unroll
  for (int ct = 0; ct < 8; ct++) {
#pragma unroll
    for (int kk = 0; kk < 4; kk++)
      B[ct][kk] = *(const bf16x8*)(wr + ((ct * 16 + col) << 7) + kk * 32 + quad * 8);
    bs[ct] = bias[(4 << 7) + ct * 16 + col];
  }
  int na = min(row0 + col, NNODES - 1);
  bf16x8 a0 = *(const bf16x8*)(x + (na << 7) + quad * 8);
  bf16x8 a1 = *(const bf16x8*)(x + (na << 7) + 32 + quad * 8);
  bf16x8 a2 = *(const bf16x8*)(x + (na << 7) + 64 + quad * 8);
  bf16x8 a3 = *(const bf16x8*)(x + (na << 7) + 96 + quad * 8);

  unsigned sl[4][NRELS];
  bool anyv[4];
#pragma unroll
  for (int j = 0; j < 4; j++) {
    int n = row0 + quad * 4 + j;
    bool a = false;
#pragma unroll
    for (int r = 0; r < NRELS; r++) {
      unsigned s = slotof[r * NNODES + n];
      sl[j][r] = s;
      a |= (s != 0xFFFFFFFFu);
    }
    anyv[j] = a;
  }

#pragma unroll
  for (int ct = 0; ct < 8; ct++) {
    f32x4 acc = {0.f, 0.f, 0.f, 0.f};
    acc = __builtin_amdgcn_mfma_f32_16x16x32_bf16(a0, B[ct][0], acc, 0, 0, 0);
    acc = __builtin_amdgcn_mfma_f32_16x16x32_bf16(a1, B[ct][1], acc, 0, 0, 0);
    acc = __builtin_amdgcn_mfma_f32_16x16x32_bf16(a2, B[ct][2], acc, 0, 0, 0);
    acc = __builtin_amdgcn_mfma_f32_16x16x32_bf16(a3, B[ct][3], acc, 0, 0, 0);
#pragma unroll
    for (int j = 0; j < 4; j++) {
      int n = row0 + quad * 4 + j;
      float m = -3.0e38f;
#pragma unroll
      for (int r = 0; r < NRELS; r++) {
        unsigned s = sl[j][r];
        if (s != 0xFFFFFFFFu)
          m = fmaxf(m, bf2f(gmax[((size_t)s << 7) + (unsigned)(ct * 16 + col)]));
      }
      float av = anyv[j] ? m : 0.f;  // DGL zero-fill for nodes w/o in-edges
      out[((size_t)n << 7) + (unsigned)(ct * 16 + col)] = acc[j] + bs[ct] + av;
    }
  }
}

extern "C" void kernel_launch(void* const* d_in, const int* in_sizes, int n_in,
                              void* d_out, int out_size, void* d_ws, size_t ws_size,
                              hipStream_t stream) {
  const float* x = (const float*)d_in[0];
  const float* W = (const float*)d_in[1];
  const float* bias = (const float*)d_in[2];
  const int* src = (const int*)d_in[3];
  const int* dst = (const int*)d_in[4];
  const int* rel = (const int*)d_in[5];

  char* ws = (char*)d_ws;
  unsigned* ssrc = (unsigned*)(ws + SSRC_OFF);
  unsigned* cnt = (unsigned*)(ws + CNT_OFF);
  unsigned* bsum = (unsigned*)(ws + BSUM_OFF);
  unsigned* ctrl = (unsigned*)(ws + CTRL_OFF);
  unsigned* lhist = (unsigned*)(ws + LHIST_OFF);
  unsigned* lbase = (unsigned*)(ws + LBASE_OFF);
  unsigned* gcur = (unsigned*)(ws + GCUR_OFF);
  unsigned* sstart = (unsigned*)(ws + SSTART_OFF);
  unsigned* slen = (unsigned*)(ws + SLEN_OFF);
  unsigned* cur = (unsigned*)(ws + CUR_OFF);
  unsigned* slotof = (unsigned*)(ws + SLOTOF_OFF);
  unsigned short* Wt = (unsigned short*)(ws + WT_OFF);
  unsigned short* xbf = (unsigned short*)(ws + XBF_OFF);
  unsigned short* gmax = (unsigned short*)(ws + GMAX_OFF);

  // zero cnt region so k_prep can fuse the (rel,dst) histogram
  hipMemsetAsync(cnt, 0, BSUM_OFF - CNT_OFF, stream);
  hipLaunchKernelGGL(k_prep, dim3(3133), dim3(256), 0, stream, x, xbf, W, Wt, rel, dst, cnt,
                     bsum, slotof);
  hipLaunchKernelGGL(k_scanA, dim3(NBLKS), dim3(256), 0, stream, cnt, bsum, lhist);
  hipLaunchKernelGGL(k_fix, dim3(NBLKS + 1), dim3(256), 0, stream, cnt, bsum, lhist, lbase,
                     ctrl);
  hipLaunchKernelGGL(k_fill, dim3(782 + 3125), dim3(256), 0, stream, rel, dst, src, cnt, lbase,
                     gcur, sstart, slen, slotof, cur, ssrc);
  hipLaunchKernelGGL(k_edge, dim3(2048), dim3(256), 0, stream, xbf, Wt, bias, ssrc, sstart, slen,
                     ctrl, gmax);
  hipLaunchKernelGGL(k_node, dim3(782), dim3(256), 0, stream, xbf, Wt, bias, slotof, gmax,
                     (float*)d_out);
}